// Round 16
// baseline (864.335 us; speedup 1.0000x reference)
//
#include <hip/hip_runtime.h>
#include <cstdint>
#include <cstddef>

namespace {
constexpr float EPS_ = 1e-5f;
}

using u16 = unsigned short;
typedef __attribute__((ext_vector_type(8))) short bf16x8;
typedef __attribute__((ext_vector_type(4))) float f32x4;

static __device__ __forceinline__ float bf2f(u16 u) {
  union { unsigned int i; float f; } x; x.i = ((unsigned int)u) << 16; return x.f;
}
static __device__ __forceinline__ u16 f2bf(float f) {
  union { float f; unsigned int i; } x; x.f = f;
  unsigned int r = x.i + 0x7fff + ((x.i >> 16) & 1);
  return (u16)(r >> 16);
}

#define OUT16(a, wv, xv) \
  a[0][0]=fmaf(wv.x,xv.x,a[0][0]); a[0][1]=fmaf(wv.x,xv.y,a[0][1]); \
  a[0][2]=fmaf(wv.x,xv.z,a[0][2]); a[0][3]=fmaf(wv.x,xv.w,a[0][3]); \
  a[1][0]=fmaf(wv.y,xv.x,a[1][0]); a[1][1]=fmaf(wv.y,xv.y,a[1][1]); \
  a[1][2]=fmaf(wv.y,xv.z,a[1][2]); a[1][3]=fmaf(wv.y,xv.w,a[1][3]); \
  a[2][0]=fmaf(wv.z,xv.x,a[2][0]); a[2][1]=fmaf(wv.z,xv.y,a[2][1]); \
  a[2][2]=fmaf(wv.z,xv.z,a[2][2]); a[2][3]=fmaf(wv.z,xv.w,a[2][3]); \
  a[3][0]=fmaf(wv.w,xv.x,a[3][0]); a[3][1]=fmaf(wv.w,xv.y,a[3][1]); \
  a[3][2]=fmaf(wv.w,xv.z,a[3][2]); a[3][3]=fmaf(wv.w,xv.w,a[3][3]);

// ---------- prep0: channel permutations sorted by floor(theta) ----------
__global__ __launch_bounds__(128) void k_prep0(
    const float* __restrict__ thin, const float* __restrict__ thout,
    int* __restrict__ perm1, int* __restrict__ perm2,
    float* __restrict__ ikPf, float* __restrict__ frP,
    float* __restrict__ ik2Pf, float* __restrict__ fr2P) {
  __shared__ float ikL[128], ik2L[128];
  const int c = threadIdx.x;
  float t1 = thin[c], t2 = thout[c];
  float f1 = floorf(t1), f2 = floorf(t2);
  ikL[c] = f1; ik2L[c] = f2;
  __syncthreads();
  int r1 = 0, r2 = 0;
  for (int j = 0; j < 128; j++) {
    r1 += (ikL[j] < f1) || (ikL[j] == f1 && j < c);
    r2 += (ik2L[j] < f2) || (ik2L[j] == f2 && j < c);
  }
  perm1[r1] = c; ikPf[r1] = f1; frP[r1] = t1 - f1;
  perm2[r2] = c; ik2Pf[r2] = f2; fr2P[r2] = t2 - f2;
}

// ---------- prep1: mask + permuted weight tables (bf16 op-major for MFMA B) ----------
__global__ __launch_bounds__(256) void k_prep1(
    const float* __restrict__ fm, const float* __restrict__ Wl,
    const float* __restrict__ dw, const float* __restrict__ rw, const float* __restrict__ tw,
    const int* __restrict__ perm1, const int* __restrict__ perm2,
    float* __restrict__ mskT, u16* __restrict__ WlB, u16* __restrict__ dwB,
    u16* __restrict__ rwB, u16* __restrict__ tlBP) {
  int i = blockIdx.x * 256 + threadIdx.x;
  if (i < 1600) { int c = i / 25, w = i % 25; mskT[c*25 + w] = tanhf(fm[w*64 + c]) + 1.0f; }
  if (i < 8192) {
    int dp = i >> 6, c = i & 63;
    WlB[i] = f2bf(Wl[c*128 + perm1[dp]]);
    dwB[i] = f2bf(dw[perm1[dp]*64 + c]);
    rwB[i] = f2bf(rw[perm2[dp]*64 + c]);
  }
  if (i < 16384) { int op = i >> 7, cp = i & 127; tlBP[i] = f2bf(tw[perm2[op]*128 + perm1[cp]]); }
}

// ---------- second moments of x: per-block partials, NO global atomics ----------
__global__ __launch_bounds__(256) void k_mom(const float* __restrict__ x,
    float* __restrict__ part) {
  __shared__ float xs[100][68];
  const int n = blockIdx.x >> 2, quarter = blockIdx.x & 3, tid = threadIdx.x;
  const int ci = (tid >> 4) * 4, cj = (tid & 15) * 4;
  float ae[4][4], ao[4][4], se[4], so[4];
  #pragma unroll
  for (int i = 0; i < 4; i++) {
    se[i] = 0.f; so[i] = 0.f;
    #pragma unroll
    for (int j = 0; j < 4; j++) { ae[i][j] = 0.f; ao[i][j] = 0.f; }
  }
  const float* xb = x + (size_t)n * 102400;
  float4 pf[7];
  #pragma unroll
  for (int k = 0; k < 7; k++) {
    int e = tid + k*256;
    if (e < 1600) { int c = e/25, q = e - c*25;
      pf[k] = *(const float4*)&xb[(size_t)c*1600 + (quarter*16)*25 + q*4]; }
  }
  for (int it = 0; it < 4; it++) {
    #pragma unroll
    for (int k = 0; k < 7; k++) {
      int e = tid + k*256;
      if (e < 1600) {
        int c = e/25, q = e - c*25;
        xs[q*4+0][c] = pf[k].x; xs[q*4+1][c] = pf[k].y;
        xs[q*4+2][c] = pf[k].z; xs[q*4+3][c] = pf[k].w;
      }
    }
    __syncthreads();
    if (it < 3) {
      const int toff = quarter*16 + (it+1)*4;
      #pragma unroll
      for (int k = 0; k < 7; k++) {
        int e = tid + k*256;
        if (e < 1600) { int c = e/25, q = e - c*25;
          pf[k] = *(const float4*)&xb[(size_t)c*1600 + toff*25 + q*4]; }
      }
    }
    #pragma unroll
    for (int tl = 0; tl < 4; tl++) {
      #pragma unroll 5
      for (int vv = 0; vv < 25; vv++) {
        const int s = tl*25 + vv;
        const float4 ra = *(const float4*)&xs[s][ci];
        const float4 rb = *(const float4*)&xs[s][cj];
        if ((tl & 1) == 0) {
          OUT16(ae, ra, rb);
          if (cj == 0) { se[0] += ra.x; se[1] += ra.y; se[2] += ra.z; se[3] += ra.w; }
        } else {
          OUT16(ao, ra, rb);
          if (cj == 0) { so[0] += ra.x; so[1] += ra.y; so[2] += ra.z; so[3] += ra.w; }
        }
      }
    }
    __syncthreads();
  }
  float* pb = part + (size_t)blockIdx.x * 8320;
  #pragma unroll
  for (int i = 0; i < 4; i++) {
    #pragma unroll
    for (int j = 0; j < 4; j++) {
      pb[tid*16 + i*4 + j]        = ae[i][j] + ao[i][j];
      pb[4096 + tid*16 + i*4 + j] = ae[i][j];
    }
  }
  if (cj == 0) {
    #pragma unroll
    for (int i = 0; i < 4; i++) {
      pb[8192 + (tid>>4)*4 + i] = se[i] + so[i];
      pb[8256 + (tid>>4)*4 + i] = se[i];
    }
  }
}

// ---------- reduce k_mom partials ----------
__global__ __launch_bounds__(256) void k_red(const float* __restrict__ part,
    float* __restrict__ Sxa, float* __restrict__ Sxe,
    float* __restrict__ suma, float* __restrict__ sume) {
  const int f = blockIdx.x*256 + threadIdx.x;
  if (f >= 8320) return;
  const int b0 = blockIdx.y * 64;
  float s = 0.f;
  for (int b = b0; b < b0 + 64; b++) s += part[(size_t)b*8320 + f];
  if (f < 8192) {
    const int half = f >> 12;
    const int q = f & 4095;
    const int t0 = q >> 4, idx = q & 15;
    const int ci = (t0 >> 4)*4 + (idx >> 2);
    const int cj = (t0 & 15)*4 + (idx & 3);
    atomicAdd(half ? &Sxe[ci*64 + cj] : &Sxa[ci*64 + cj], s);
  } else if (f < 8256) {
    atomicAdd(&suma[f - 8192], s);
  } else {
    atomicAdd(&sume[f - 8256], s);
  }
}

// ---------- analytic bn scale/shift for down (perm1) & res (perm2) ----------
__global__ __launch_bounds__(256) void k_fin(
    const float* __restrict__ dw, const float* __restrict__ dbg, const float* __restrict__ dbb,
    const float* __restrict__ rw, const float* __restrict__ rbg, const float* __restrict__ rbb,
    const int* __restrict__ perm1, const int* __restrict__ perm2,
    const float* __restrict__ Sxa, const float* __restrict__ Sxe,
    const float* __restrict__ suma, const float* __restrict__ sume,
    float* __restrict__ scDP, float* __restrict__ shDP,
    float* __restrict__ scRP, float* __restrict__ shRP) {
  __shared__ float SA[4096], SE[4096], sa[64], seL[64];
  const int tid = threadIdx.x;
  for (int i = tid; i < 4096; i += 256) { SA[i] = Sxa[i]; SE[i] = Sxe[i]; }
  if (tid < 64) { sa[tid] = suma[tid]; seL[tid] = sume[tid]; }
  __syncthreads();
  const bool down = tid < 128;
  const int p = tid & 127;
  const int o = down ? perm1[p] : perm2[p];
  const float* w = down ? dw : rw;
  const float* SS = down ? SA : SE;
  const float* sv = down ? sa : seL;
  const float iS = down ? (1.f/409600.f) : (1.f/204800.f);
  float wr[64];
  #pragma unroll
  for (int c = 0; c < 64; c += 4) {
    float4 t = *(const float4*)&w[o*64 + c];
    wr[c] = t.x; wr[c+1] = t.y; wr[c+2] = t.z; wr[c+3] = t.w;
  }
  float mu = 0.f, q = 0.f;
  for (int c = 0; c < 64; c++) {
    mu = fmaf(wr[c], sv[c], mu);
    float pp = 0.f;
    #pragma unroll 8
    for (int c2 = 0; c2 < 64; c2++) pp = fmaf(SS[c*64 + c2], wr[c2], pp);
    q = fmaf(wr[c], pp, q);
  }
  mu *= iS; q *= iS;
  float var = fmaxf(q - mu*mu, 0.f);
  float g = down ? dbg[o] : rbg[o];
  float b = down ? dbb[o] : rbb[o];
  float sc = g * rsqrtf(var + EPS_);
  if (down) { scDP[p] = sc; shDP[p] = b - mu*sc; }
  else      { scRP[p] = sc; shRP[p] = b - mu*sc; }
}

// ---------- K1 (fused MFMA, 4 subs/block): GCN GEMM -> A  AND  down GEMM -> D ----------
// Register prefetch across subs hides stage-load latency under MFMA+epilogue.
// Epilogue buffers overlay dead staging space. LDS ~27.7 KB.
__global__ __launch_bounds__(256) void k1(
    const float* __restrict__ x, const u16* __restrict__ WlB, const u16* __restrict__ dwB,
    const float* __restrict__ mskT, const int* __restrict__ perm1,
    u16* __restrict__ A, u16* __restrict__ D) {
  __shared__ __align__(16) u16 smem[13600];  // phase A: xsT[64][72] | xmT[64][72]; phase B: ysD[50][136] | ysA[50][136]
  __shared__ int dmL[128];
  u16* xsT = smem;
  u16* xmT = smem + 4608;
  u16* ysD = smem;
  u16* ysA = smem + 6800;
  const int tgb = blockIdx.x * 4, n = blockIdx.y, tid = threadIdx.x;
  if (tid < 128) dmL[tid] = perm1[tid] % 25;
  const float* xb = x + (size_t)n * 102400;
  const int w = tid >> 6, l = tid & 63;
  const int lc = l & 15, kg = l >> 4;
  float2 pf[7];
  #pragma unroll
  for (int k = 0; k < 7; k++) {
    int e = tid + k*256;
    if (e < 1600) { int c = e/25, q = e - c*25;
      pf[k] = *(const float2*)&xb[(size_t)c*1600 + (size_t)(tgb*2)*25 + q*2]; }
  }
  for (int sub = 0; sub < 4; sub++) {
    const int t2 = (tgb + sub) * 2;
    // stage current sub from registers
    #pragma unroll
    for (int k = 0; k < 7; k++) {
      int e = tid + k*256;
      if (e < 1600) {
        int c = e/25, q = e - c*25;
        int cm = c; if (cm >= 50) cm -= 50; else if (cm >= 25) cm -= 25;
        const int s0 = q*2, s1 = q*2 + 1;
        const int tl0 = (s0 >= 25), v0 = s0 - tl0*25;
        const int tl1 = (s1 >= 25), v1 = s1 - tl1*25;
        xsT[s0*72 + c] = f2bf(pf[k].x);
        xsT[s1*72 + c] = f2bf(pf[k].y);
        int w0 = v0 - cm; if (w0 < 0) w0 += 25;
        int w1 = v1 - cm; if (w1 < 0) w1 += 25;
        xmT[(tl0*25 + w0)*72 + c] = f2bf(pf[k].x * mskT[c*25 + w0]);
        xmT[(tl1*25 + w1)*72 + c] = f2bf(pf[k].y * mskT[c*25 + w1]);
      }
    }
    // issue next sub's loads (latency hides under MFMA+epilogue)
    if (sub < 3) {
      #pragma unroll
      for (int k = 0; k < 7; k++) {
        int e = tid + k*256;
        if (e < 1600) { int c = e/25, q = e - c*25;
          pf[k] = *(const float2*)&xb[(size_t)c*1600 + (size_t)((tgb + sub + 1)*2)*25 + q*2]; }
      }
    }
    __syncthreads();
    f32x4 accA[8], accD[8];
    #pragma unroll
    for (int nt = 0; nt < 8; nt++) {
      accA[nt][0]=0.f; accA[nt][1]=0.f; accA[nt][2]=0.f; accA[nt][3]=0.f;
      accD[nt][0]=0.f; accD[nt][1]=0.f; accD[nt][2]=0.f; accD[nt][3]=0.f;
    }
    #pragma unroll
    for (int ks = 0; ks < 2; ks++) {
      const bf16x8 am = *(const bf16x8*)&xmT[(w*16 + lc)*72 + ks*32 + kg*8];
      const bf16x8 ax = *(const bf16x8*)&xsT[(w*16 + lc)*72 + ks*32 + kg*8];
      #pragma unroll
      for (int nt = 0; nt < 8; nt++) {
        const bf16x8 bW = *(const bf16x8*)&WlB[(size_t)(nt*16 + lc)*64 + ks*32 + kg*8];
        const bf16x8 bD = *(const bf16x8*)&dwB[(size_t)(nt*16 + lc)*64 + ks*32 + kg*8];
        accA[nt] = __builtin_amdgcn_mfma_f32_16x16x32_bf16(am, bW, accA[nt], 0, 0, 0);
        accD[nt] = __builtin_amdgcn_mfma_f32_16x16x32_bf16(ax, bD, accD[nt], 0, 0, 0);
      }
    }
    __syncthreads();   // LDS reads drained -> staging space reusable as ys
    #pragma unroll
    for (int nt = 0; nt < 8; nt++) {
      const int dp = nt*16 + lc;
      const int dm = dmL[dp];
      #pragma unroll
      for (int r = 0; r < 4; r++) {
        const int s = w*16 + kg*4 + r;
        if (s < 50) {
          ysD[s*136 + dp] = f2bf(accD[nt][r]);
          int tl = 0, wv = s; if (wv >= 25) { tl = 1; wv -= 25; }
          int v = wv + dm; if (v >= 25) v -= 25;
          ysA[(tl*25 + v)*136 + dp] = f2bf(accA[nt][r]);
        }
      }
    }
    __syncthreads();
    u16* Dslab = D + (size_t)n*204800 + (size_t)t2*3200;
    u16* Aslab = A + (size_t)n*204800 + (size_t)t2*3200;
    for (int i = tid; i < 1600; i += 256) {
      if (i < 800) {
        int s = i >> 4, ch = i & 15;
        *(int4*)(Dslab + s*128 + ch*8) = *(const int4*)&ysD[s*136 + ch*8];
      } else {
        int j = i - 800;
        int s = j >> 4, ch = j & 15;
        *(int4*)(Aslab + s*128 + ch*8) = *(const int4*)&ysA[s*136 + ch*8];
      }
    }
    __syncthreads();   // copy-out reads done before next sub's staging writes
  }
}

// ---------- stats over 3200 features (v,dp) of A ----------
__global__ __launch_bounds__(256) void k_statsA(const u16* __restrict__ A,
    float* __restrict__ gs1, float* __restrict__ gs2) {
  const int foct = blockIdx.x*256 + threadIdx.x;
  if (foct >= 400) return;
  const int rb = blockIdx.y * 128;
  const size_t f0 = (size_t)foct * 8;
  float s1[8], s2[8];
  #pragma unroll
  for (int i = 0; i < 8; i++) { s1[i] = 0.f; s2[i] = 0.f; }
  for (int r = 0; r < 128; r++) {
    union { int4 i4; u16 u[8]; } raw;
    raw.i4 = *(const int4*)(A + (size_t)(rb + r)*3200 + f0);
    #pragma unroll
    for (int i = 0; i < 8; i++) { float v = bf2f(raw.u[i]); s1[i] += v; s2[i] = fmaf(v, v, s2[i]); }
  }
  #pragma unroll
  for (int i = 0; i < 8; i++) { atomicAdd(&gs1[f0+i], s1[i]); atomicAdd(&gs2[f0+i], s2[i]); }
}

// ---------- finalize gcn bn scale/shift per (v,dp) ----------
__global__ __launch_bounds__(256) void k_fin2(
    const float* __restrict__ gs1, const float* __restrict__ gs2,
    const float* __restrict__ gg, const float* __restrict__ gb,
    const int* __restrict__ perm1,
    float* __restrict__ scG, float* __restrict__ shG) {
  int f = blockIdx.x*256 + threadIdx.x;
  if (f >= 3200) return;
  int v = f >> 7, dp = f & 127;
  int d = perm1[dp];
  float m = gs1[f] * (1.f/16384.f);
  float var = fmaxf(gs2[f]*(1.f/16384.f) - m*m, 0.f);
  float r = rsqrtf(var + EPS_);
  float sc = gg[v*128 + d] * r;
  scG[f] = sc; shG[f] = gb[v*128 + d] - m*sc;
}

// ---------- K2f: streaming y = relu(bn1d(h)+bn(down)) with fused ts1/ts2 stats ----------
__global__ __launch_bounds__(256) void k2f(
    u16* __restrict__ A, const u16* __restrict__ D,
    const float* __restrict__ scG, const float* __restrict__ shG,
    const float* __restrict__ scDP, const float* __restrict__ shDP,
    float* __restrict__ ts1, float* __restrict__ ts2) {
  const int tid = threadIdx.x;
  const int f0 = (tid & 15) * 8;
  const int rg = tid >> 4;
  const long rb = (long)blockIdx.x * 400;
  float sD[8], hD[8];
  #pragma unroll
  for (int i = 0; i < 8; i++) { sD[i] = scDP[f0+i]; hD[i] = shDP[f0+i]; }
  float s1[8], s2[8];
  #pragma unroll
  for (int i = 0; i < 8; i++) { s1[i] = 0.f; s2[i] = 0.f; }
  for (int r = rg; r < 400; r += 16) {
    const long row = rb + r;
    const int v = (int)(row % 25);
    union { int4 i4; u16 u[8]; } araw, draw, o;
    araw.i4 = *(const int4*)(A + row*128 + f0);
    draw.i4 = *(const int4*)(D + row*128 + f0);
    const float4 g0 = *(const float4*)&scG[v*128 + f0];
    const float4 g1 = *(const float4*)&scG[v*128 + f0 + 4];
    const float4 b0 = *(const float4*)&shG[v*128 + f0];
    const float4 b1 = *(const float4*)&shG[v*128 + f0 + 4];
    const float gg_[8] = {g0.x,g0.y,g0.z,g0.w,g1.x,g1.y,g1.z,g1.w};
    const float bb_[8] = {b0.x,b0.y,b0.z,b0.w,b1.x,b1.y,b1.z,b1.w};
    #pragma unroll
    for (int i = 0; i < 8; i++) {
      float y = fmaf(bf2f(araw.u[i]), gg_[i], bb_[i]) + fmaf(bf2f(draw.u[i]), sD[i], hD[i]);
      y = fmaxf(y, 0.f);
      s1[i] += y; s2[i] = fmaf(y, y, s2[i]);
      o.u[i] = f2bf(y);
    }
    *(int4*)(A + row*128 + f0) = o.i4;
  }
  __shared__ float m1[16][128], m2[16][128];
  #pragma unroll
  for (int i = 0; i < 8; i++) { m1[rg][f0+i] = s1[i]; m2[rg][f0+i] = s2[i]; }
  __syncthreads();
  if (tid < 128) {
    float a = 0.f, b = 0.f;
    #pragma unroll
    for (int g = 0; g < 16; g++) { a += m1[g][tid]; b += m2[g][tid]; }
    atomicAdd(&ts1[tid], a); atomicAdd(&ts2[tid], b);
  }
}

// ---------- per-128-channel stats (channel-last rows) ----------
__global__ __launch_bounds__(256) void k_statsP(const u16* __restrict__ P, long nrows,
    float* __restrict__ s1g, float* __restrict__ s2g) {
  const int tid = threadIdx.x;
  const int f0 = (tid & 15) * 8;
  const int rg = tid >> 4;
  long rpb = nrows / gridDim.x;
  long rb = (long)blockIdx.x * rpb;
  float s1[8], s2[8];
  #pragma unroll
  for (int i = 0; i < 8; i++) { s1[i] = 0.f; s2[i] = 0.f; }
  for (long r = rg; r < rpb; r += 16) {
    union { int4 i4; u16 u[8]; } raw;
    raw.i4 = *(const int4*)(P + (rb + r)*128 + f0);
    #pragma unroll
    for (int i = 0; i < 8; i++) { float v = bf2f(raw.u[i]); s1[i] += v; s2[i] = fmaf(v, v, s2[i]); }
  }
  __shared__ float m1[16][128], m2[16][128];
  #pragma unroll
  for (int i = 0; i < 8; i++) { m1[rg][f0+i] = s1[i]; m2[rg][f0+i] = s2[i]; }
  __syncthreads();
  if (tid < 128) {
    float a = 0.f, b = 0.f;
    #pragma unroll
    for (int g = 0; g < 16; g++) { a += m1[g][tid]; b += m2[g][tid]; }
    atomicAdd(&s1g[tid], a); atomicAdd(&s2g[tid], b);
  }
}

// ---------- K3 (MFMA, TB=4): bn(y)+shift(theta_in,1)+tl GEMM+bias+relu -> Z bf16 (d_out) ----------
__global__ __launch_bounds__(256) void k3(
    const u16* __restrict__ Y,
    const float* __restrict__ ts1, const float* __restrict__ ts2,
    const float* __restrict__ tgamma, const float* __restrict__ tbeta,
    const int* __restrict__ perm1, const int* __restrict__ perm2,
    const float* __restrict__ ikPf, const float* __restrict__ frP,
    const u16* __restrict__ tlBP, const float* __restrict__ tlb,
    u16* __restrict__ Z) {
  __shared__ __align__(16) u16 smem[128*136];
  __shared__ float scL[128], shL[128], frL[128], tlbL[128];
  __shared__ int ikL[128];
  const int tg = blockIdx.x, n = blockIdx.y, tid = threadIdx.x;
  const int t4 = tg * 4;
  if (tid < 128) {
    int cp = tid, c = perm1[cp];
    float m = ts1[cp] * (1.f/409600.f);
    float var = fmaxf(ts2[cp]*(1.f/409600.f) - m*m, 0.f);
    float r = rsqrtf(var + EPS_);
    float sc = tgamma[c] * r;
    scL[cp] = sc; shL[cp] = tbeta[c] - m*sc;
    ikL[cp] = (int)ikPf[cp]; frL[cp] = frP[cp];
    tlbL[cp] = tlb[perm2[cp]];
  }
  __syncthreads();
  const u16* Yb = Y + (size_t)n * 204800;
  for (int e = tid; e < 3200; e += 256) {
    int cp = e & 127, v = e >> 7;
    int ik = ikL[cp];
    float fr = frL[cp], sc = scL[cp], sh = shL[cp];
    const u16* base = Yb + v*128 + cp;
    float y[5];
    #pragma unroll
    for (int j = 0; j < 5; j++) {
      int t = t4 + ik + j;
      y[j] = (t >= 0 && t < 64) ? fmaf(bf2f(base[(size_t)t*3200]), sc, sh) : 0.f;
    }
    #pragma unroll
    for (int tl = 0; tl < 4; tl++)
      smem[(tl*25 + v)*136 + cp] = f2bf((1.f - fr)*y[tl] + fr*y[tl+1]);
  }
  __syncthreads();
  const int w = tid >> 6, l = tid & 63;
  const int lc = l & 15, kg = l >> 4;
  bf16x8 a[2][4];
  #pragma unroll
  for (int mi = 0; mi < 2; mi++) {
    const int row = (w + mi*4)*16 + lc;
    #pragma unroll
    for (int ks = 0; ks < 4; ks++)
      a[mi][ks] = *(const bf16x8*)&smem[row*136 + ks*32 + kg*8];
  }
  __syncthreads();
  #pragma unroll
  for (int nt = 0; nt < 8; nt++) {
    const int op = nt*16 + lc;
    bf16x8 b[4];
    #pragma unroll
    for (int ks = 0; ks < 4; ks++)
      b[ks] = *(const bf16x8*)&tlBP[(size_t)op*128 + ks*32 + kg*8];
    const float bb = tlbL[op];
    #pragma unroll
    for (int mi = 0; mi < 2; mi++) {
      f32x4 acc; acc[0]=bb; acc[1]=bb; acc[2]=bb; acc[3]=bb;
      #pragma unroll
      for (int ks = 0; ks < 4; ks++)
        acc = __builtin_amdgcn_mfma_f32_16x16x32_bf16(a[mi][ks], b[ks], acc, 0, 0, 0);
      #pragma unroll
      for (int r = 0; r < 4; r++) {
        const int s = (w + mi*4)*16 + kg*4 + r;
        if (s < 100) smem[s*136 + op] = f2bf(fmaxf(acc[r], 0.f));
      }
    }
  }
  __syncthreads();
  u16* Zb = Z + (size_t)n*204800 + (size_t)t4*3200;
  for (int i = tid; i < 1600; i += 256) {
    int s = i >> 4, ch = i & 15;
    *(int4*)(Zb + s*128 + ch*8) = *(const int4*)&smem[s*136 + ch*8];
  }
}

// ---------- K4: stride-2 shift(theta_out) Z -> C[n][tp][v][op] bf16 ----------
__global__ __launch_bounds__(256) void k4(const u16* __restrict__ Z,
    const float* __restrict__ ik2Pf, const float* __restrict__ fr2P,
    u16* __restrict__ C) {
  __shared__ int ikL[128];
  __shared__ float frL[128];
  if (threadIdx.x < 128) { ikL[threadIdx.x] = (int)ik2Pf[threadIdx.x]; frL[threadIdx.x] = fr2P[threadIdx.x]; }
  __syncthreads();
  for (size_t idx = (size_t)blockIdx.x*256 + threadIdx.x; idx < 26214400ull; idx += (size_t)gridDim.x*256) {
    int op = (int)(idx & 127);
    int v  = (int)((idx >> 7) % 25);
    int tp = (int)((idx / 3200) & 31);
    int n  = (int)(idx / 102400);
    int t0 = 2*tp + ikL[op];
    float fr = frL[op];
    const u16* base = Z + (size_t)n*204800 + v*128 + op;
    float a0 = (t0 >= 0 && t0 < 64) ? bf2f(base[(size_t)t0*3200]) : 0.f;
    int t1 = t0 + 1;
    float a1 = (t1 >= 0 && t1 < 64) ? bf2f(base[(size_t)t1*3200]) : 0.f;
    C[idx] = f2bf((1.f - fr)*a0 + fr*a1);
  }
}

// ---------- K5 (MFMA, 8tp/block): res GEMM + out = relu(bn2(C)+bn(res)) -> NCHW fp32 ----------
__global__ __launch_bounds__(256) void k5(
    const float* __restrict__ x, const u16* __restrict__ C,
    const u16* __restrict__ rwB,
    const float* __restrict__ scRP, const float* __restrict__ shRP,
    const float* __restrict__ zs1, const float* __restrict__ zs2,
    const float* __restrict__ t2g, const float* __restrict__ t2b,
    const int* __restrict__ perm2, float* __restrict__ out) {
  __shared__ __align__(16) u16 xsT[50][72];
  __shared__ __align__(16) u16 ch[6400];
  __shared__ float ys[128][52];
  __shared__ float sc2L[128], sh2L[128];
  __shared__ int p2L[128];
  const int tpg = blockIdx.x, n = blockIdx.y, tid = threadIdx.x;
  if (tid < 128) {
    int op = tid, o = perm2[op];
    float m = zs1[op] * (1.f/204800.f);
    float var = fmaxf(zs2[op]*(1.f/204800.f) - m*m, 0.f);
    float r = rsqrtf(var + EPS_);
    float sc = t2g[o] * r;
    sc2L[op] = sc; sh2L[op] = t2b[o] - m*sc;
    p2L[op] = o;
  }
  const float* xb = x + (size_t)n * 102400;
  const int w = tid >> 6, l = tid & 63;
  const int lc = l & 15, kg = l >> 4;
  for (int sub = 0; sub < 4; sub++) {
    const int tp2 = tpg*8 + sub*2;
    for (int e = tid; e < 3200; e += 256) {
      int tl = e / 1600, r = e - tl*1600, c = r / 25, v = r - c*25;
      xsT[tl*25 + v][c] = f2bf(xb[(size_t)c*1600 + 2*(tp2+tl)*25 + v]);
    }
    {
      int4* dst = (int4*)ch;
      const int4* src = (const int4*)(C + (size_t)n*102400 + (size_t)tp2*3200);
      for (int i = tid; i < 800; i += 256) dst[i] = src[i];
    }
    __syncthreads();
    f32x4 acc[8];
    #pragma unroll
    for (int nt = 0; nt < 8; nt++) { acc[nt][0]=0.f; acc[nt][1]=0.f; acc[nt][2]=0.f; acc[nt][3]=0.f; }
    #pragma unroll
    for (int ks = 0; ks < 2; ks++) {
      const bf16x8 a = *(const bf16x8*)&xsT[w*16 + lc][ks*32 + kg*8];
      #pragma unroll
      for (int nt = 0; nt < 8; nt++) {
        const bf16x8 b = *(const bf16x8*)&rwB[(size_t)(nt*16 + lc)*64 + ks*32 + kg*8];
        acc[nt] = __builtin_amdgcn_mfma_f32_16x16x32_bf16(a, b, acc[nt], 0, 0, 0);
      }
    }
    #pragma unroll
    for (int nt = 0; nt < 8; nt++) {
      const int op = nt*16 + lc;
      const float sR = scRP[op], hR = shRP[op];
      const float sz = sc2L[op], hz = sh2L[op];
      #pragma unroll
      for (int r = 0; r < 4; r++) {
        const int s = w*16 + kg*4 + r;
        if (s < 50) {
          float zv = fmaf(bf2f(ch[s*128 + op]), sz, hz);
          float rv = fmaf(acc[nt][r], sR, hR);
          ys[op][s] = fmaxf(zv + rv, 0.f);
        }
      }
    }
    __syncthreads();
    for (int i = tid; i < 6400; i += 256) {
      int op = i / 50, k = i - op*50;
      out[((size_t)(n*128 + p2L[op]))*800 + tp2*25 + k] = ys[op][k];
    }
    __syncthreads();
  }
}

extern "C" void kernel_launch(void* const* d_in, const int* in_sizes, int n_in,
                              void* d_out, int out_size, void* d_ws, size_t ws_size,
                              hipStream_t stream) {
  (void)in_sizes; (void)n_in; (void)out_size;
  if (ws_size < 105200000ull) return;  // clean fail instead of OOB crash
  const float* x     = (const float*)d_in[0];
  const float* Wl    = (const float*)d_in[1];
  const float* fm    = (const float*)d_in[3];
  const float* gg    = (const float*)d_in[4];
  const float* gb    = (const float*)d_in[5];
  const float* dw    = (const float*)d_in[6];
  const float* dbg   = (const float*)d_in[8];
  const float* dbb   = (const float*)d_in[9];
  const float* tgam  = (const float*)d_in[10];
  const float* tbet  = (const float*)d_in[11];
  const float* thin  = (const float*)d_in[12];
  const float* tw    = (const float*)d_in[13];
  const float* tlb   = (const float*)d_in[14];
  const float* thout = (const float*)d_in[15];
  const float* t2g   = (const float*)d_in[16];
  const float* t2b   = (const float*)d_in[17];
  const float* rw    = (const float*)d_in[18];
  const float* rbg   = (const float*)d_in[20];
  const float* rbb   = (const float*)d_in[21];
  float* out = (float*)d_out;
  u16* Zd = (u16*)d_out;            // d_out hosts: D (k1->k2f), then Z (k3->k4), then final out
  u16* Dd = (u16*)d_out;

  u16* A  = (u16*)d_ws;             // [256][64][25][128] bf16 = 104,857,600 B
  u16* Cb = A;                      // C aliases A (A dead after k3)
  float* part = (float*)d_ws;       // k_mom partials (34 MB) — dead before k1 writes A
  float* mskT = (float*)((char*)d_ws + 104857600);   // 1600 f
  u16*  WlB   = (u16*)(mskT + 1600);                 // 8192 u16
  u16*  dwB   = WlB + 8192;                          // 8192 u16
  u16*  rwB   = dwB + 8192;                          // 8192 u16
  u16*  tlBP  = (u16*)((float*)(dwB + 8192) + 8192); // 16384 u16
  float* scG  = (float*)(tlBP + 16384);              // 3200
  float* shG  = scG + 3200;         // 3200
  float* scDP = shG + 3200;         // 128
  float* shDP = scDP + 128;
  float* scRP = shDP + 128;
  float* shRP = scRP + 128;
  float* ikPf = shRP + 128;
  float* frP  = ikPf + 128;
  float* ik2Pf= frP + 128;
  float* fr2P = ik2Pf + 128;
  float* Sxa  = fr2P + 128;         // zero region start (15232 floats)
  float* Sxe  = Sxa + 4096;
  float* suma = Sxe + 4096;
  float* sume = suma + 64;
  float* gs1  = sume + 64;
  float* gs2  = gs1 + 3200;
  float* ts1  = gs2 + 3200;
  float* ts2  = ts1 + 128;
  float* zs1  = ts2 + 128;
  float* zs2  = zs1 + 128;
  int* perm1  = (int*)(zs2 + 128);
  int* perm2  = perm1 + 128;

  (void)hipMemsetAsync(Sxa, 0, 15232 * sizeof(float), stream);
  k_prep0<<<1, 128, 0, stream>>>(thin, thout, perm1, perm2, ikPf, frP, ik2Pf, fr2P);
  k_prep1<<<64, 256, 0, stream>>>(fm, Wl, dw, rw, tw, perm1, perm2, mskT, WlB, dwB, rwB, tlBP);
  k_mom<<<1024, 256, 0, stream>>>(x, part);
  k_red<<<dim3(33, 16), 256, 0, stream>>>(part, Sxa, Sxe, suma, sume);
  k_fin<<<1, 256, 0, stream>>>(dw, dbg, dbb, rw, rbg, rbb, perm1, perm2,
                               Sxa, Sxe, suma, sume, scDP, shDP, scRP, shRP);
  k1<<<dim3(8, 256), 256, 0, stream>>>(x, WlB, dwB, mskT, perm1, A, Dd);
  k_statsA<<<dim3(2, 128), 256, 0, stream>>>(A, gs1, gs2);
  k_fin2<<<13, 256, 0, stream>>>(gs1, gs2, gg, gb, perm1, scG, shG);
  k2f<<<1024, 256, 0, stream>>>(A, Dd, scG, shG, scDP, shDP, ts1, ts2);
  k3<<<dim3(16, 256), 256, 0, stream>>>(A, ts1, ts2, tgam, tbet, perm1, perm2,
                                        ikPf, frP, tlBP, tlb, Zd);
  k4<<<2048, 256, 0, stream>>>(Zd, ik2Pf, fr2P, Cb);
  k_statsP<<<400, 256, 0, stream>>>(Cb, 204800L, zs1, zs2);
  k5<<<dim3(4, 256), 256, 0, stream>>>(x, Cb, rwB, scRP, shRP, zs1, zs2, t2g, t2b, perm2, out);
}

// Round 17
// 833.592 us; speedup vs baseline: 1.0369x; 1.0369x over previous
//
#include <hip/hip_runtime.h>
#include <cstdint>
#include <cstddef>

namespace {
constexpr float EPS_ = 1e-5f;
}

using u16 = unsigned short;
typedef __attribute__((ext_vector_type(8))) short bf16x8;
typedef __attribute__((ext_vector_type(4))) float f32x4;

static __device__ __forceinline__ float bf2f(u16 u) {
  union { unsigned int i; float f; } x; x.i = ((unsigned int)u) << 16; return x.f;
}
static __device__ __forceinline__ u16 f2bf(float f) {
  union { float f; unsigned int i; } x; x.f = f;
  unsigned int r = x.i + 0x7fff + ((x.i >> 16) & 1);
  return (u16)(r >> 16);
}

#define OUT16(a, wv, xv) \
  a[0][0]=fmaf(wv.x,xv.x,a[0][0]); a[0][1]=fmaf(wv.x,xv.y,a[0][1]); \
  a[0][2]=fmaf(wv.x,xv.z,a[0][2]); a[0][3]=fmaf(wv.x,xv.w,a[0][3]); \
  a[1][0]=fmaf(wv.y,xv.x,a[1][0]); a[1][1]=fmaf(wv.y,xv.y,a[1][1]); \
  a[1][2]=fmaf(wv.y,xv.z,a[1][2]); a[1][3]=fmaf(wv.y,xv.w,a[1][3]); \
  a[2][0]=fmaf(wv.z,xv.x,a[2][0]); a[2][1]=fmaf(wv.z,xv.y,a[2][1]); \
  a[2][2]=fmaf(wv.z,xv.z,a[2][2]); a[2][3]=fmaf(wv.z,xv.w,a[2][3]); \
  a[3][0]=fmaf(wv.w,xv.x,a[3][0]); a[3][1]=fmaf(wv.w,xv.y,a[3][1]); \
  a[3][2]=fmaf(wv.w,xv.z,a[3][2]); a[3][3]=fmaf(wv.w,xv.w,a[3][3]);

// ---------- prep0: channel permutations sorted by floor(theta) ----------
__global__ __launch_bounds__(128) void k_prep0(
    const float* __restrict__ thin, const float* __restrict__ thout,
    int* __restrict__ perm1, int* __restrict__ perm2,
    float* __restrict__ ikPf, float* __restrict__ frP,
    float* __restrict__ ik2Pf, float* __restrict__ fr2P) {
  __shared__ float ikL[128], ik2L[128];
  const int c = threadIdx.x;
  float t1 = thin[c], t2 = thout[c];
  float f1 = floorf(t1), f2 = floorf(t2);
  ikL[c] = f1; ik2L[c] = f2;
  __syncthreads();
  int r1 = 0, r2 = 0;
  for (int j = 0; j < 128; j++) {
    r1 += (ikL[j] < f1) || (ikL[j] == f1 && j < c);
    r2 += (ik2L[j] < f2) || (ik2L[j] == f2 && j < c);
  }
  perm1[r1] = c; ikPf[r1] = f1; frP[r1] = t1 - f1;
  perm2[r2] = c; ik2Pf[r2] = f2; fr2P[r2] = t2 - f2;
}

// ---------- prep1: mask + permuted weight tables (bf16 op-major for MFMA B) ----------
__global__ __launch_bounds__(256) void k_prep1(
    const float* __restrict__ fm, const float* __restrict__ Wl,
    const float* __restrict__ dw, const float* __restrict__ rw, const float* __restrict__ tw,
    const int* __restrict__ perm1, const int* __restrict__ perm2,
    float* __restrict__ mskT, u16* __restrict__ WlB, u16* __restrict__ dwB,
    u16* __restrict__ rwB, u16* __restrict__ tlBP) {
  int i = blockIdx.x * 256 + threadIdx.x;
  if (i < 1600) { int c = i / 25, w = i % 25; mskT[c*25 + w] = tanhf(fm[w*64 + c]) + 1.0f; }
  if (i < 8192) {
    int dp = i >> 6, c = i & 63;
    WlB[i] = f2bf(Wl[c*128 + perm1[dp]]);
    dwB[i] = f2bf(dw[perm1[dp]*64 + c]);
    rwB[i] = f2bf(rw[perm2[dp]*64 + c]);
  }
  if (i < 16384) { int op = i >> 7, cp = i & 127; tlBP[i] = f2bf(tw[perm2[op]*128 + perm1[cp]]); }
}

// ---------- second moments of x + emit bf16 channel-last xbT[(n,t,v)][c] ----------
__global__ __launch_bounds__(256) void k_mom(const float* __restrict__ x,
    float* __restrict__ part, u16* __restrict__ xbT) {
  __shared__ float xs[100][68];
  const int n = blockIdx.x >> 2, quarter = blockIdx.x & 3, tid = threadIdx.x;
  const int ci = (tid >> 4) * 4, cj = (tid & 15) * 4;
  float ae[4][4], ao[4][4], se[4], so[4];
  #pragma unroll
  for (int i = 0; i < 4; i++) {
    se[i] = 0.f; so[i] = 0.f;
    #pragma unroll
    for (int j = 0; j < 4; j++) { ae[i][j] = 0.f; ao[i][j] = 0.f; }
  }
  const float* xb = x + (size_t)n * 102400;
  float4 pf[7];
  #pragma unroll
  for (int k = 0; k < 7; k++) {
    int e = tid + k*256;
    if (e < 1600) { int c = e/25, q = e - c*25;
      pf[k] = *(const float4*)&xb[(size_t)c*1600 + (quarter*16)*25 + q*4]; }
  }
  for (int it = 0; it < 4; it++) {
    const int toffc = quarter*16 + it*4;
    #pragma unroll
    for (int k = 0; k < 7; k++) {
      int e = tid + k*256;
      if (e < 1600) {
        int c = e/25, q = e - c*25;
        xs[q*4+0][c] = pf[k].x; xs[q*4+1][c] = pf[k].y;
        xs[q*4+2][c] = pf[k].z; xs[q*4+3][c] = pf[k].w;
      }
    }
    __syncthreads();
    // dump bf16 transposed copy (coalesced int4 writes)
    for (int i = tid; i < 800; i += 256) {
      int sl = i >> 3, oc = (i & 7) * 8;
      union { int4 i4; u16 u[8]; } r;
      #pragma unroll
      for (int j = 0; j < 8; j++) r.u[j] = f2bf(xs[sl][oc + j]);
      *(int4*)&xbT[((size_t)n*1600 + toffc*25 + sl)*64 + oc] = r.i4;
    }
    if (it < 3) {
      const int toff = quarter*16 + (it+1)*4;
      #pragma unroll
      for (int k = 0; k < 7; k++) {
        int e = tid + k*256;
        if (e < 1600) { int c = e/25, q = e - c*25;
          pf[k] = *(const float4*)&xb[(size_t)c*1600 + toff*25 + q*4]; }
      }
    }
    #pragma unroll
    for (int tl = 0; tl < 4; tl++) {
      #pragma unroll 5
      for (int vv = 0; vv < 25; vv++) {
        const int s = tl*25 + vv;
        const float4 ra = *(const float4*)&xs[s][ci];
        const float4 rb = *(const float4*)&xs[s][cj];
        if ((tl & 1) == 0) {
          OUT16(ae, ra, rb);
          if (cj == 0) { se[0] += ra.x; se[1] += ra.y; se[2] += ra.z; se[3] += ra.w; }
        } else {
          OUT16(ao, ra, rb);
          if (cj == 0) { so[0] += ra.x; so[1] += ra.y; so[2] += ra.z; so[3] += ra.w; }
        }
      }
    }
    __syncthreads();
  }
  float* pb = part + (size_t)blockIdx.x * 8320;
  #pragma unroll
  for (int i = 0; i < 4; i++) {
    #pragma unroll
    for (int j = 0; j < 4; j++) {
      pb[tid*16 + i*4 + j]        = ae[i][j] + ao[i][j];
      pb[4096 + tid*16 + i*4 + j] = ae[i][j];
    }
  }
  if (cj == 0) {
    #pragma unroll
    for (int i = 0; i < 4; i++) {
      pb[8192 + (tid>>4)*4 + i] = se[i] + so[i];
      pb[8256 + (tid>>4)*4 + i] = se[i];
    }
  }
}

// ---------- reduce k_mom partials ----------
__global__ __launch_bounds__(256) void k_red(const float* __restrict__ part,
    float* __restrict__ Sxa, float* __restrict__ Sxe,
    float* __restrict__ suma, float* __restrict__ sume) {
  const int f = blockIdx.x*256 + threadIdx.x;
  if (f >= 8320) return;
  const int b0 = blockIdx.y * 64;
  float s = 0.f;
  for (int b = b0; b < b0 + 64; b++) s += part[(size_t)b*8320 + f];
  if (f < 8192) {
    const int half = f >> 12;
    const int q = f & 4095;
    const int t0 = q >> 4, idx = q & 15;
    const int ci = (t0 >> 4)*4 + (idx >> 2);
    const int cj = (t0 & 15)*4 + (idx & 3);
    atomicAdd(half ? &Sxe[ci*64 + cj] : &Sxa[ci*64 + cj], s);
  } else if (f < 8256) {
    atomicAdd(&suma[f - 8192], s);
  } else {
    atomicAdd(&sume[f - 8256], s);
  }
}

// ---------- analytic bn scale/shift for down (perm1) & res (perm2) ----------
__global__ __launch_bounds__(256) void k_fin(
    const float* __restrict__ dw, const float* __restrict__ dbg, const float* __restrict__ dbb,
    const float* __restrict__ rw, const float* __restrict__ rbg, const float* __restrict__ rbb,
    const int* __restrict__ perm1, const int* __restrict__ perm2,
    const float* __restrict__ Sxa, const float* __restrict__ Sxe,
    const float* __restrict__ suma, const float* __restrict__ sume,
    float* __restrict__ scDP, float* __restrict__ shDP,
    float* __restrict__ scRP, float* __restrict__ shRP) {
  __shared__ float SA[4096], SE[4096], sa[64], seL[64];
  const int tid = threadIdx.x;
  for (int i = tid; i < 4096; i += 256) { SA[i] = Sxa[i]; SE[i] = Sxe[i]; }
  if (tid < 64) { sa[tid] = suma[tid]; seL[tid] = sume[tid]; }
  __syncthreads();
  const bool down = tid < 128;
  const int p = tid & 127;
  const int o = down ? perm1[p] : perm2[p];
  const float* w = down ? dw : rw;
  const float* SS = down ? SA : SE;
  const float* sv = down ? sa : seL;
  const float iS = down ? (1.f/409600.f) : (1.f/204800.f);
  float wr[64];
  #pragma unroll
  for (int c = 0; c < 64; c += 4) {
    float4 t = *(const float4*)&w[o*64 + c];
    wr[c] = t.x; wr[c+1] = t.y; wr[c+2] = t.z; wr[c+3] = t.w;
  }
  float mu = 0.f, q = 0.f;
  for (int c = 0; c < 64; c++) {
    mu = fmaf(wr[c], sv[c], mu);
    float pp = 0.f;
    #pragma unroll 8
    for (int c2 = 0; c2 < 64; c2++) pp = fmaf(SS[c*64 + c2], wr[c2], pp);
    q = fmaf(wr[c], pp, q);
  }
  mu *= iS; q *= iS;
  float var = fmaxf(q - mu*mu, 0.f);
  float g = down ? dbg[o] : rbg[o];
  float b = down ? dbb[o] : rbb[o];
  float sc = g * rsqrtf(var + EPS_);
  if (down) { scDP[p] = sc; shDP[p] = b - mu*sc; }
  else      { scRP[p] = sc; shRP[p] = b - mu*sc; }
}

// ---------- K1 (fused MFMA): GCN GEMM -> A  AND  down GEMM -> D (bf16, lives in d_out) ----------
// bf16 channel-last input xbT: coalesced int4 staging; xmT derived from registers.
// Epilogue buffers overlay dead staging space. LDS ~27.7 KB.
__global__ __launch_bounds__(256) void k1(
    const u16* __restrict__ xbT, const u16* __restrict__ WlB, const u16* __restrict__ dwB,
    const float* __restrict__ mskT, const int* __restrict__ perm1,
    u16* __restrict__ A, u16* __restrict__ D) {
  __shared__ __align__(16) u16 smem[13600];  // phase A: xsT[64][72] | xmT[64][72]; phase B: ysD[50][136] | ysA[50][136]
  __shared__ int dmL[128];
  u16* xsT = smem;
  u16* xmT = smem + 4608;
  u16* ysD = smem;
  u16* ysA = smem + 6800;
  const int tg = blockIdx.x, n = blockIdx.y, tid = threadIdx.x;
  const int t2 = tg * 2;
  if (tid < 128) dmL[tid] = perm1[tid] % 25;
  const u16* xrow = xbT + ((size_t)n*1600 + (size_t)t2*25)*64;   // 50 rows x 64 c
  for (int i = tid; i < 400; i += 256) {
    int s = i >> 3, oc = (i & 7) * 8;
    int tl = (s >= 25), v = s - tl*25;
    union { int4 i4; u16 u[8]; } r;
    r.i4 = *(const int4*)&xrow[(size_t)s*64 + oc];
    *(int4*)&xsT[s*72 + oc] = r.i4;
    #pragma unroll
    for (int j = 0; j < 8; j++) {
      int c = oc + j;
      int cm = c; if (cm >= 50) cm -= 50; else if (cm >= 25) cm -= 25;
      int w0 = v - cm; if (w0 < 0) w0 += 25;
      xmT[(tl*25 + w0)*72 + c] = f2bf(bf2f(r.u[j]) * mskT[c*25 + w0]);
    }
  }
  __syncthreads();
  const int w = tid >> 6, l = tid & 63;
  const int lc = l & 15, kg = l >> 4;
  f32x4 accA[8], accD[8];
  #pragma unroll
  for (int nt = 0; nt < 8; nt++) {
    accA[nt][0]=0.f; accA[nt][1]=0.f; accA[nt][2]=0.f; accA[nt][3]=0.f;
    accD[nt][0]=0.f; accD[nt][1]=0.f; accD[nt][2]=0.f; accD[nt][3]=0.f;
  }
  #pragma unroll
  for (int ks = 0; ks < 2; ks++) {
    const bf16x8 am = *(const bf16x8*)&xmT[(w*16 + lc)*72 + ks*32 + kg*8];
    const bf16x8 ax = *(const bf16x8*)&xsT[(w*16 + lc)*72 + ks*32 + kg*8];
    #pragma unroll
    for (int nt = 0; nt < 8; nt++) {
      const bf16x8 bW = *(const bf16x8*)&WlB[(size_t)(nt*16 + lc)*64 + ks*32 + kg*8];
      const bf16x8 bD = *(const bf16x8*)&dwB[(size_t)(nt*16 + lc)*64 + ks*32 + kg*8];
      accA[nt] = __builtin_amdgcn_mfma_f32_16x16x32_bf16(am, bW, accA[nt], 0, 0, 0);
      accD[nt] = __builtin_amdgcn_mfma_f32_16x16x32_bf16(ax, bD, accD[nt], 0, 0, 0);
    }
  }
  __syncthreads();   // all LDS reads drained -> staging space reusable
  #pragma unroll
  for (int nt = 0; nt < 8; nt++) {
    const int dp = nt*16 + lc;
    const int dm = dmL[dp];
    #pragma unroll
    for (int r = 0; r < 4; r++) {
      const int s = w*16 + kg*4 + r;
      if (s < 50) {
        ysD[s*136 + dp] = f2bf(accD[nt][r]);
        int tl = 0, wv = s; if (wv >= 25) { tl = 1; wv -= 25; }
        int v = wv + dm; if (v >= 25) v -= 25;
        ysA[(tl*25 + v)*136 + dp] = f2bf(accA[nt][r]);
      }
    }
  }
  __syncthreads();
  u16* Dslab = D + (size_t)n*204800 + (size_t)t2*3200;
  u16* Aslab = A + (size_t)n*204800 + (size_t)t2*3200;
  for (int i = tid; i < 1600; i += 256) {
    if (i < 800) {
      int s = i >> 4, ch = i & 15;
      *(int4*)(Dslab + s*128 + ch*8) = *(const int4*)&ysD[s*136 + ch*8];
    } else {
      int j = i - 800;
      int s = j >> 4, ch = j & 15;
      *(int4*)(Aslab + s*128 + ch*8) = *(const int4*)&ysA[s*136 + ch*8];
    }
  }
}

// ---------- stats over 3200 features (v,dp) of A ----------
__global__ __launch_bounds__(256) void k_statsA(const u16* __restrict__ A,
    float* __restrict__ gs1, float* __restrict__ gs2) {
  const int foct = blockIdx.x*256 + threadIdx.x;
  if (foct >= 400) return;
  const int rb = blockIdx.y * 64;
  const size_t f0 = (size_t)foct * 8;
  float s1[8], s2[8];
  #pragma unroll
  for (int i = 0; i < 8; i++) { s1[i] = 0.f; s2[i] = 0.f; }
  for (int r = 0; r < 64; r++) {
    union { int4 i4; u16 u[8]; } raw;
    raw.i4 = *(const int4*)(A + (size_t)(rb + r)*3200 + f0);
    #pragma unroll
    for (int i = 0; i < 8; i++) { float v = bf2f(raw.u[i]); s1[i] += v; s2[i] = fmaf(v, v, s2[i]); }
  }
  #pragma unroll
  for (int i = 0; i < 8; i++) { atomicAdd(&gs1[f0+i], s1[i]); atomicAdd(&gs2[f0+i], s2[i]); }
}

// ---------- finalize gcn bn scale/shift per (v,dp) ----------
__global__ __launch_bounds__(256) void k_fin2(
    const float* __restrict__ gs1, const float* __restrict__ gs2,
    const float* __restrict__ gg, const float* __restrict__ gb,
    const int* __restrict__ perm1,
    float* __restrict__ scG, float* __restrict__ shG) {
  int f = blockIdx.x*256 + threadIdx.x;
  if (f >= 3200) return;
  int v = f >> 7, dp = f & 127;
  int d = perm1[dp];
  float m = gs1[f] * (1.f/16384.f);
  float var = fmaxf(gs2[f]*(1.f/16384.f) - m*m, 0.f);
  float r = rsqrtf(var + EPS_);
  float sc = gg[v*128 + d] * r;
  scG[f] = sc; shG[f] = gb[v*128 + d] - m*sc;
}

// ---------- K2f: streaming y = relu(bn1d(h)+bn(down)) with fused ts1/ts2 stats ----------
__global__ __launch_bounds__(256) void k2f(
    u16* __restrict__ A, const u16* __restrict__ D,
    const float* __restrict__ scG, const float* __restrict__ shG,
    const float* __restrict__ scDP, const float* __restrict__ shDP,
    float* __restrict__ ts1, float* __restrict__ ts2) {
  const int tid = threadIdx.x;
  const int f0 = (tid & 15) * 8;
  const int rg = tid >> 4;
  const long rb = (long)blockIdx.x * 200;
  float sD[8], hD[8];
  #pragma unroll
  for (int i = 0; i < 8; i++) { sD[i] = scDP[f0+i]; hD[i] = shDP[f0+i]; }
  float s1[8], s2[8];
  #pragma unroll
  for (int i = 0; i < 8; i++) { s1[i] = 0.f; s2[i] = 0.f; }
  for (int r = rg; r < 200; r += 16) {
    const long row = rb + r;
    const int v = (int)(row % 25);
    union { int4 i4; u16 u[8]; } araw, draw, o;
    araw.i4 = *(const int4*)(A + row*128 + f0);
    draw.i4 = *(const int4*)(D + row*128 + f0);
    const float4 g0 = *(const float4*)&scG[v*128 + f0];
    const float4 g1 = *(const float4*)&scG[v*128 + f0 + 4];
    const float4 b0 = *(const float4*)&shG[v*128 + f0];
    const float4 b1 = *(const float4*)&shG[v*128 + f0 + 4];
    const float gg_[8] = {g0.x,g0.y,g0.z,g0.w,g1.x,g1.y,g1.z,g1.w};
    const float bb_[8] = {b0.x,b0.y,b0.z,b0.w,b1.x,b1.y,b1.z,b1.w};
    #pragma unroll
    for (int i = 0; i < 8; i++) {
      float y = fmaf(bf2f(araw.u[i]), gg_[i], bb_[i]) + fmaf(bf2f(draw.u[i]), sD[i], hD[i]);
      y = fmaxf(y, 0.f);
      s1[i] += y; s2[i] = fmaf(y, y, s2[i]);
      o.u[i] = f2bf(y);
    }
    *(int4*)(A + row*128 + f0) = o.i4;
  }
  __shared__ float m1[16][128], m2[16][128];
  #pragma unroll
  for (int i = 0; i < 8; i++) { m1[rg][f0+i] = s1[i]; m2[rg][f0+i] = s2[i]; }
  __syncthreads();
  if (tid < 128) {
    float a = 0.f, b = 0.f;
    #pragma unroll
    for (int g = 0; g < 16; g++) { a += m1[g][tid]; b += m2[g][tid]; }
    atomicAdd(&ts1[tid], a); atomicAdd(&ts2[tid], b);
  }
}

// ---------- per-128-channel stats (channel-last rows) ----------
__global__ __launch_bounds__(256) void k_statsP(const u16* __restrict__ P, long nrows,
    float* __restrict__ s1g, float* __restrict__ s2g) {
  const int tid = threadIdx.x;
  const int f0 = (tid & 15) * 8;
  const int rg = tid >> 4;
  long rpb = nrows / gridDim.x;
  long rb = (long)blockIdx.x * rpb;
  float s1[8], s2[8];
  #pragma unroll
  for (int i = 0; i < 8; i++) { s1[i] = 0.f; s2[i] = 0.f; }
  for (long r = rg; r < rpb; r += 16) {
    union { int4 i4; u16 u[8]; } raw;
    raw.i4 = *(const int4*)(P + (rb + r)*128 + f0);
    #pragma unroll
    for (int i = 0; i < 8; i++) { float v = bf2f(raw.u[i]); s1[i] += v; s2[i] = fmaf(v, v, s2[i]); }
  }
  __shared__ float m1[16][128], m2[16][128];
  #pragma unroll
  for (int i = 0; i < 8; i++) { m1[rg][f0+i] = s1[i]; m2[rg][f0+i] = s2[i]; }
  __syncthreads();
  if (tid < 128) {
    float a = 0.f, b = 0.f;
    #pragma unroll
    for (int g = 0; g < 16; g++) { a += m1[g][tid]; b += m2[g][tid]; }
    atomicAdd(&s1g[tid], a); atomicAdd(&s2g[tid], b);
  }
}

// ---------- K3 (MFMA, TB=4): bn(y)+shift(theta_in,1)+tl GEMM+bias+relu -> Z bf16 (d_out) ----------
__global__ __launch_bounds__(256) void k3(
    const u16* __restrict__ Y,
    const float* __restrict__ ts1, const float* __restrict__ ts2,
    const float* __restrict__ tgamma, const float* __restrict__ tbeta,
    const int* __restrict__ perm1, const int* __restrict__ perm2,
    const float* __restrict__ ikPf, const float* __restrict__ frP,
    const u16* __restrict__ tlBP, const float* __restrict__ tlb,
    u16* __restrict__ Z) {
  __shared__ __align__(16) u16 smem[128*136];
  __shared__ float scL[128], shL[128], frL[128], tlbL[128];
  __shared__ int ikL[128];
  const int tg = blockIdx.x, n = blockIdx.y, tid = threadIdx.x;
  const int t4 = tg * 4;
  if (tid < 128) {
    int cp = tid, c = perm1[cp];
    float m = ts1[cp] * (1.f/409600.f);
    float var = fmaxf(ts2[cp]*(1.f/409600.f) - m*m, 0.f);
    float r = rsqrtf(var + EPS_);
    float sc = tgamma[c] * r;
    scL[cp] = sc; shL[cp] = tbeta[c] - m*sc;
    ikL[cp] = (int)ikPf[cp]; frL[cp] = frP[cp];
    tlbL[cp] = tlb[perm2[cp]];
  }
  __syncthreads();
  const u16* Yb = Y + (size_t)n * 204800;
  for (int e = tid; e < 3200; e += 256) {
    int cp = e & 127, v = e >> 7;
    int ik = ikL[cp];
    float fr = frL[cp], sc = scL[cp], sh = shL[cp];
    const u16* base = Yb + v*128 + cp;
    float y[5];
    #pragma unroll
    for (int j = 0; j < 5; j++) {
      int t = t4 + ik + j;
      y[j] = (t >= 0 && t < 64) ? fmaf(bf2f(base[(size_t)t*3200]), sc, sh) : 0.f;
    }
    #pragma unroll
    for (int tl = 0; tl < 4; tl++)
      smem[(tl*25 + v)*136 + cp] = f2bf((1.f - fr)*y[tl] + fr*y[tl+1]);
  }
  __syncthreads();
  const int w = tid >> 6, l = tid & 63;
  const int lc = l & 15, kg = l >> 4;
  bf16x8 a[2][4];
  #pragma unroll
  for (int mi = 0; mi < 2; mi++) {
    const int row = (w + mi*4)*16 + lc;
    #pragma unroll
    for (int ks = 0; ks < 4; ks++)
      a[mi][ks] = *(const bf16x8*)&smem[row*136 + ks*32 + kg*8];
  }
  __syncthreads();
  #pragma unroll
  for (int nt = 0; nt < 8; nt++) {
    const int op = nt*16 + lc;
    bf16x8 b[4];
    #pragma unroll
    for (int ks = 0; ks < 4; ks++)
      b[ks] = *(const bf16x8*)&tlBP[(size_t)op*128 + ks*32 + kg*8];
    const float bb = tlbL[op];
    #pragma unroll
    for (int mi = 0; mi < 2; mi++) {
      f32x4 acc; acc[0]=bb; acc[1]=bb; acc[2]=bb; acc[3]=bb;
      #pragma unroll
      for (int ks = 0; ks < 4; ks++)
        acc = __builtin_amdgcn_mfma_f32_16x16x32_bf16(a[mi][ks], b[ks], acc, 0, 0, 0);
      #pragma unroll
      for (int r = 0; r < 4; r++) {
        const int s = (w + mi*4)*16 + kg*4 + r;
        if (s < 100) smem[s*136 + op] = f2bf(fmaxf(acc[r], 0.f));
      }
    }
  }
  __syncthreads();
  u16* Zb = Z + (size_t)n*204800 + (size_t)t4*3200;
  for (int i = tid; i < 1600; i += 256) {
    int s = i >> 4, ch = i & 15;
    *(int4*)(Zb + s*128 + ch*8) = *(const int4*)&smem[s*136 + ch*8];
  }
}

// ---------- K4: stride-2 shift(theta_out) Z -> C[n][tp][v][op] bf16 ----------
__global__ __launch_bounds__(256) void k4(const u16* __restrict__ Z,
    const float* __restrict__ ik2Pf, const float* __restrict__ fr2P,
    u16* __restrict__ C) {
  __shared__ int ikL[128];
  __shared__ float frL[128];
  if (threadIdx.x < 128) { ikL[threadIdx.x] = (int)ik2Pf[threadIdx.x]; frL[threadIdx.x] = fr2P[threadIdx.x]; }
  __syncthreads();
  for (size_t idx = (size_t)blockIdx.x*256 + threadIdx.x; idx < 26214400ull; idx += (size_t)gridDim.x*256) {
    int op = (int)(idx & 127);
    int v  = (int)((idx >> 7) % 25);
    int tp = (int)((idx / 3200) & 31);
    int n  = (int)(idx / 102400);
    int t0 = 2*tp + ikL[op];
    float fr = frL[op];
    const u16* base = Z + (size_t)n*204800 + v*128 + op;
    float a0 = (t0 >= 0 && t0 < 64) ? bf2f(base[(size_t)t0*3200]) : 0.f;
    int t1 = t0 + 1;
    float a1 = (t1 >= 0 && t1 < 64) ? bf2f(base[(size_t)t1*3200]) : 0.f;
    C[idx] = f2bf((1.f - fr)*a0 + fr*a1);
  }
}

// ---------- K5 (MFMA, 8tp/block): res GEMM + out = relu(bn2(C)+bn(res)) -> NCHW fp32 ----------
__global__ __launch_bounds__(256) void k5(
    const u16* __restrict__ xbT, const u16* __restrict__ C,
    const u16* __restrict__ rwB,
    const float* __restrict__ scRP, const float* __restrict__ shRP,
    const float* __restrict__ zs1, const float* __restrict__ zs2,
    const float* __restrict__ t2g, const float* __restrict__ t2b,
    const int* __restrict__ perm2, float* __restrict__ out) {
  __shared__ __align__(16) u16 xsT[50][72];
  __shared__ __align__(16) u16 ch[6400];
  __shared__ float ys[128][52];
  __shared__ float sc2L[128], sh2L[128];
  __shared__ int p2L[128];
  const int tpg = blockIdx.x, n = blockIdx.y, tid = threadIdx.x;
  if (tid < 128) {
    int op = tid, o = perm2[op];
    float m = zs1[op] * (1.f/204800.f);
    float var = fmaxf(zs2[op]*(1.f/204800.f) - m*m, 0.f);
    float r = rsqrtf(var + EPS_);
    float sc = t2g[o] * r;
    sc2L[op] = sc; sh2L[op] = t2b[o] - m*sc;
    p2L[op] = o;
  }
  const u16* xnb = xbT + (size_t)n*1600*64;
  const int w = tid >> 6, l = tid & 63;
  const int lc = l & 15, kg = l >> 4;
  for (int sub = 0; sub < 4; sub++) {
    const int tp2 = tpg*8 + sub*2;
    for (int i = tid; i < 400; i += 256) {
      int s = i >> 3, oc = (i & 7) * 8;
      int tl = (s >= 25), v = s - tl*25;
      *(int4*)&xsT[s][oc] = *(const int4*)&xnb[((size_t)(2*(tp2+tl))*25 + v)*64 + oc];
    }
    {
      int4* dst = (int4*)ch;
      const int4* src = (const int4*)(C + (size_t)n*102400 + (size_t)tp2*3200);
      for (int i = tid; i < 800; i += 256) dst[i] = src[i];
    }
    __syncthreads();
    f32x4 acc[8];
    #pragma unroll
    for (int nt = 0; nt < 8; nt++) { acc[nt][0]=0.f; acc[nt][1]=0.f; acc[nt][2]=0.f; acc[nt][3]=0.f; }
    #pragma unroll
    for (int ks = 0; ks < 2; ks++) {
      const bf16x8 a = *(const bf16x8*)&xsT[w*16 + lc][ks*32 + kg*8];
      #pragma unroll
      for (int nt = 0; nt < 8; nt++) {
        const bf16x8 b = *(const bf16x8*)&rwB[(size_t)(nt*16 + lc)*64 + ks*32 + kg*8];
        acc[nt] = __builtin_amdgcn_mfma_f32_16x16x32_bf16(a, b, acc[nt], 0, 0, 0);
      }
    }
    #pragma unroll
    for (int nt = 0; nt < 8; nt++) {
      const int op = nt*16 + lc;
      const float sR = scRP[op], hR = shRP[op];
      const float sz = sc2L[op], hz = sh2L[op];
      #pragma unroll
      for (int r = 0; r < 4; r++) {
        const int s = w*16 + kg*4 + r;
        if (s < 50) {
          float zv = fmaf(bf2f(ch[s*128 + op]), sz, hz);
          float rv = fmaf(acc[nt][r], sR, hR);
          ys[op][s] = fmaxf(zv + rv, 0.f);
        }
      }
    }
    __syncthreads();
    for (int i = tid; i < 6400; i += 256) {
      int op = i / 50, k = i - op*50;
      out[((size_t)(n*128 + p2L[op]))*800 + tp2*25 + k] = ys[op][k];
    }
    __syncthreads();
  }
}

extern "C" void kernel_launch(void* const* d_in, const int* in_sizes, int n_in,
                              void* d_out, int out_size, void* d_ws, size_t ws_size,
                              hipStream_t stream) {
  (void)in_sizes; (void)n_in; (void)out_size;
  if (ws_size < 157466368ull) return;  // clean fail instead of OOB crash (proven >= 157486848 available)
  const float* x     = (const float*)d_in[0];
  const float* Wl    = (const float*)d_in[1];
  const float* fm    = (const float*)d_in[3];
  const float* gg    = (const float*)d_in[4];
  const float* gb    = (const float*)d_in[5];
  const float* dw    = (const float*)d_in[6];
  const float* dbg   = (const float*)d_in[8];
  const float* dbb   = (const float*)d_in[9];
  const float* tgam  = (const float*)d_in[10];
  const float* tbet  = (const float*)d_in[11];
  const float* thin  = (const float*)d_in[12];
  const float* tw    = (const float*)d_in[13];
  const float* tlb   = (const float*)d_in[14];
  const float* thout = (const float*)d_in[15];
  const float* t2g   = (const float*)d_in[16];
  const float* t2b   = (const float*)d_in[17];
  const float* rw    = (const float*)d_in[18];
  const float* rbg   = (const float*)d_in[20];
  const float* rbb   = (const float*)d_in[21];
  float* out = (float*)d_out;
  u16* Zd = (u16*)d_out;            // d_out hosts: D (k1->k2f), then Z (k3->k4), then final out
  u16* Dd = (u16*)d_out;

  char* wsb = (char*)d_ws;
  u16* A   = (u16*)wsb;                     // [0, 104857600): A / C / part overlays
  u16* Cb  = A;
  float* part = (float*)wsb;
  u16* xbT = (u16*)(wsb + 104857600);       // 26,214,400 u16 = 52,428,800 B
  float* mskT = (float*)(wsb + 157286400);  // params
  u16*  WlB   = (u16*)(mskT + 1600);
  u16*  dwB   = WlB + 8192;
  u16*  rwB   = dwB + 8192;
  u16*  tlBP  = (u16*)((float*)(dwB + 8192) + 8192);
  float* scG  = (float*)(tlBP + 16384);
  float* shG  = scG + 3200;
  float* scDP = shG + 3200;
  float* shDP = scDP + 128;
  float* scRP = shDP + 128;
  float* shRP = scRP + 128;
  float* ikPf = shRP + 128;
  float* frP  = ikPf + 128;
  float* ik2Pf= frP + 128;
  float* fr2P = ik2Pf + 128;
  float* Sxa  = fr2P + 128;         // zero region start (15232 floats)
  float* Sxe  = Sxa + 4096;
  float* suma = Sxe + 4096;
  float* sume = suma + 64;
  float* gs1  = sume + 64;
  float* gs2  = gs1 + 3200;
  float* ts1  = gs2 + 3200;
  float* ts2  = ts1 + 128;
  float* zs1  = ts2 + 128;
  float* zs2  = zs1 + 128;
  int* perm1  = (int*)(zs2 + 128);
  int* perm2  = perm1 + 128;

  (void)hipMemsetAsync(Sxa, 0, 15232 * sizeof(float), stream);
  k_prep0<<<1, 128, 0, stream>>>(thin, thout, perm1, perm2, ikPf, frP, ik2Pf, fr2P);
  k_prep1<<<64, 256, 0, stream>>>(fm, Wl, dw, rw, tw, perm1, perm2, mskT, WlB, dwB, rwB, tlBP);
  k_mom<<<1024, 256, 0, stream>>>(x, part, xbT);
  k_red<<<dim3(33, 16), 256, 0, stream>>>(part, Sxa, Sxe, suma, sume);
  k_fin<<<1, 256, 0, stream>>>(dw, dbg, dbb, rw, rbg, rbb, perm1, perm2,
                               Sxa, Sxe, suma, sume, scDP, shDP, scRP, shRP);
  k1<<<dim3(32, 256), 256, 0, stream>>>(xbT, WlB, dwB, mskT, perm1, A, Dd);
  k_statsA<<<dim3(2, 256), 256, 0, stream>>>(A, gs1, gs2);
  k_fin2<<<13, 256, 0, stream>>>(gs1, gs2, gg, gb, perm1, scG, shG);
  k2f<<<2048, 256, 0, stream>>>(A, Dd, scG, shG, scDP, shDP, ts1, ts2);
  k3<<<dim3(16, 256), 256, 0, stream>>>(A, ts1, ts2, tgam, tbet, perm1, perm2,
                                        ikPf, frP, tlBP, tlb, Zd);
  k4<<<2048, 256, 0, stream>>>(Zd, ik2Pf, fr2P, Cb);
  k_statsP<<<400, 256, 0, stream>>>(Cb, 204800L, zs1, zs2);
  k5<<<dim3(4, 256), 256, 0, stream>>>(xbT, Cb, rwB, scRP, shRP, zs1, zs2, t2g, t2b, perm2, out);
}